// Round 1
// 623.726 us; speedup vs baseline: 1.5126x; 1.5126x over previous
//
#include <hip/hip_runtime.h>
#include <hip/hip_bf16.h>

// Problem constants (compile-time; n_heads input d_in[9] ignored).
// Inputs/outputs FLOAT32 (per reference). Intermediates 16-bit in d_ws.
// R6: out_gemm rewritten as fp16 MFMA (m97 128x128 structure + T2 swizzle +
//     global_load_lds w16). AO now stored fp16; Wo converted to fp16 WoT[n][k].
#define BB      4
#define SEQ     4096
#define DMODEL  1024
#define NHEAD   16
#define DK      64
#define LK      256
#define BH      (BB*NHEAD)   // 64

typedef unsigned short u16;
typedef unsigned int   u32;
typedef float f32x4  __attribute__((ext_vector_type(4)));
typedef short bf16x8 __attribute__((ext_vector_type(8)));
typedef _Float16 f16x8 __attribute__((ext_vector_type(8)));

__device__ __forceinline__ float bf2f(u16 x) { return __uint_as_float(((u32)x) << 16); }
__device__ __forceinline__ u16 f2bf(float f) {
    u32 u = __float_as_uint(f);
    u32 r = u + 0x7fffu + ((u >> 16) & 1u);   // round-nearest-even
    return (u16)(r >> 16);
}
__device__ __forceinline__ u16 f2h(float f) {
    _Float16 h = (_Float16)f;                 // v_cvt_f16_f32, RNE
    u16 r; __builtin_memcpy(&r, &h, 2); return r;
}
// unpack 8 bf16 (uint4) -> 8 floats
__device__ __forceinline__ void unpack8(uint4 r, float* f) {
    f[0] = __uint_as_float(r.x << 16); f[1] = __uint_as_float(r.x & 0xffff0000u);
    f[2] = __uint_as_float(r.y << 16); f[3] = __uint_as_float(r.y & 0xffff0000u);
    f[4] = __uint_as_float(r.z << 16); f[5] = __uint_as_float(r.z & 0xffff0000u);
    f[6] = __uint_as_float(r.w << 16); f[7] = __uint_as_float(r.w & 0xffff0000u);
}
__device__ __forceinline__ u32 packbf(float a, float b) {
    return (u32)f2bf(a) | ((u32)f2bf(b) << 16);
}
__device__ __forceinline__ u32 packh(float a, float b) {
    return (u32)f2h(a) | ((u32)f2h(b) << 16);
}
// async global->LDS, 16B per lane (dest must be wave-uniform base + lane*16)
__device__ __forceinline__ void gl2lds16(const void* g, void* l) {
    __builtin_amdgcn_global_load_lds(
        (const __attribute__((address_space(1))) unsigned int*)g,
        (__attribute__((address_space(3))) unsigned int*)l,
        16, 0, 0);
}

// ---------------------------------------------------------------------------
// Kernel 1: projections. (unchanged this round)
// z=0: KpT[bh][LK][DK] = sum_n We[n,k]*K[b,n,h*64+d] + be[k]   (d contiguous)
// z=1: VpT[bh][DK][LK] = sum_n Wf[n,k]*V[b,n,h*64+d] + bf[k]   (k contiguous!)
// ---------------------------------------------------------------------------
__global__ __launch_bounds__(256) void proj_kernel(
    const float* __restrict__ Kin, const float* __restrict__ Vin,
    const float* __restrict__ We,  const float* __restrict__ be,
    const float* __restrict__ Wf,  const float* __restrict__ bfp,
    u16* __restrict__ KpT, u16* __restrict__ VpT)
{
    const int kq = blockIdx.x;            // k0 = kq*64
    const int bh = blockIdx.y;
    const int b  = bh >> 4, h = bh & 15;
    const int isV = blockIdx.z;
    const float* Inp  = isV ? Vin : Kin;
    const float* W    = isV ? Wf  : We;
    const float* bias = isV ? bfp : be;
    u16* Out          = isV ? VpT : KpT;

    __shared__ float Wl[64][68];          // [nn][k_local]
    __shared__ float Il[64][68];          // [nn][d]

    const int t  = threadIdx.x;
    const int k0 = kq * 64;
    const int kg = t >> 4;                // k_local = kg*4
    const int dg = t & 15;                // d = dg*4

    float acc[4][4];
#pragma unroll
    for (int i = 0; i < 4; ++i)
#pragma unroll
        for (int j = 0; j < 4; ++j) acc[i][j] = 0.f;

    for (int n0 = 0; n0 < SEQ; n0 += 64) {
        __syncthreads();
#pragma unroll
        for (int pass = 0; pass < 2; ++pass) {
            int idx = t + pass * 256;
            int nn  = idx >> 3;
            int c8  = (idx & 7) * 8;
            const float* wsrc = W + (size_t)(n0 + nn) * LK + k0 + c8;
            *(float4*)&Wl[nn][c8]     = *(const float4*)(wsrc);
            *(float4*)&Wl[nn][c8 + 4] = *(const float4*)(wsrc + 4);
            const float* isrc = Inp + ((size_t)b * SEQ + n0 + nn) * DMODEL + h * DK + c8;
            *(float4*)&Il[nn][c8]     = *(const float4*)(isrc);
            *(float4*)&Il[nn][c8 + 4] = *(const float4*)(isrc + 4);
        }
        __syncthreads();
#pragma unroll 8
        for (int nn = 0; nn < 64; ++nn) {
            const float4 w4 = *(const float4*)&Wl[nn][kg * 4];
            const float4 i4 = *(const float4*)&Il[nn][dg * 4];
            acc[0][0] += w4.x * i4.x; acc[0][1] += w4.x * i4.y; acc[0][2] += w4.x * i4.z; acc[0][3] += w4.x * i4.w;
            acc[1][0] += w4.y * i4.x; acc[1][1] += w4.y * i4.y; acc[1][2] += w4.y * i4.z; acc[1][3] += w4.y * i4.w;
            acc[2][0] += w4.z * i4.x; acc[2][1] += w4.z * i4.y; acc[2][2] += w4.z * i4.z; acc[2][3] += w4.z * i4.w;
            acc[3][0] += w4.w * i4.x; acc[3][1] += w4.w * i4.y; acc[3][2] += w4.w * i4.z; acc[3][3] += w4.w * i4.w;
        }
    }

    if (!isV) {
        // KpT[bh][k][d]: pack 4 d for each of 4 k
#pragma unroll
        for (int i = 0; i < 4; ++i) {
            int k = k0 + kg * 4 + i;
            float bv = bias[k];
            uint2 o = make_uint2(packbf(acc[i][0] + bv, acc[i][1] + bv),
                                 packbf(acc[i][2] + bv, acc[i][3] + bv));
            *(uint2*)(Out + ((size_t)bh * LK + k) * DK + dg * 4) = o;
        }
    } else {
        // VpT[bh][d][k]: pack 4 consecutive k for each of 4 d (bias varies with k)
        float bv0 = bias[k0 + kg * 4 + 0], bv1 = bias[k0 + kg * 4 + 1];
        float bv2 = bias[k0 + kg * 4 + 2], bv3 = bias[k0 + kg * 4 + 3];
#pragma unroll
        for (int j = 0; j < 4; ++j) {
            int d = dg * 4 + j;
            uint2 o = make_uint2(packbf(acc[0][j] + bv0, acc[1][j] + bv1),
                                 packbf(acc[2][j] + bv2, acc[3][j] + bv3));
            *(uint2*)(Out + ((size_t)bh * DK + d) * LK + k0 + kg * 4) = o;
        }
    }
}

// ---------------------------------------------------------------------------
// Kernel 2 (MFMA): fused scores+softmax+PV. Block = 64 Q-rows x one (b,h),
// 4 waves, wave w owns rows w*16..w*16+15 end-to-end (no cross-wave deps).
// A layout: A[m=lane&15][k=quad*8+j]; B: B[k=quad*8+j][n=lane&15];
// C/D: col=lane&15, row=quad*4+reg  (learn_hip m89/m91/m120 verified).
// R6 change: final AO store is fp16 (feeds fp16 MFMA out_gemm).
// ---------------------------------------------------------------------------
__global__ __launch_bounds__(256) void attn_mfma(
    const float* __restrict__ Qin, const u16* __restrict__ KpT,
    const u16* __restrict__ VpT,   u16* __restrict__ AO)
{
    const int bh = blockIdx.y, b = bh >> 4, h = bh & 15;
    const int n0 = blockIdx.x * 64;
    const int t  = threadIdx.x;
    const int w    = t >> 6;          // wave 0..3
    const int lane = t & 63;
    const int q    = lane >> 4;       // quad 0..3
    const int c    = lane & 15;

    __shared__ u16 Qs[64][72];        // Q tile bf16 (+8 pad: 144B stride, 2-way free)
    __shared__ u16 Pl[64][264];       // P tile bf16 (+8 pad: 528B stride, 16B aligned)

    // ---- stage Q (fp32 -> bf16), wave w stages its own 16 rows ----
    {
        int lr = lane >> 2, col0 = (lane & 3) * 16;
        const float* src = Qin + ((size_t)b * SEQ + n0 + w * 16 + lr) * DMODEL + h * DK + col0;
        float4 f0 = ((const float4*)src)[0];
        float4 f1 = ((const float4*)src)[1];
        float4 f2 = ((const float4*)src)[2];
        float4 f3 = ((const float4*)src)[3];
        uint4 p0, p1;
        p0.x = packbf(f0.x, f0.y); p0.y = packbf(f0.z, f0.w);
        p0.z = packbf(f1.x, f1.y); p0.w = packbf(f1.z, f1.w);
        p1.x = packbf(f2.x, f2.y); p1.y = packbf(f2.z, f2.w);
        p1.z = packbf(f3.x, f3.y); p1.w = packbf(f3.z, f3.w);
        *(uint4*)&Qs[w * 16 + lr][col0]     = p0;
        *(uint4*)&Qs[w * 16 + lr][col0 + 8] = p1;
    }
    __syncthreads();   // cheap paranoia; all deps are wave-local

    // ---- A-fragments for QK^T (row m = w*16 + c, k = d) ----
    bf16x8 a0 = *(const bf16x8*)&Qs[w * 16 + c][q * 8];
    bf16x8 a1 = *(const bf16x8*)&Qs[w * 16 + c][32 + q * 8];

    // ---- scores: 16 col-tiles of 16 lk each; B-frags straight from L2 ----
    f32x4 sc[16];
#pragma unroll
    for (int nt = 0; nt < 16; ++nt) sc[nt] = (f32x4){0.f, 0.f, 0.f, 0.f};

    const u16* kb = KpT + (size_t)bh * LK * DK;
#pragma unroll
    for (int nt = 0; nt < 16; ++nt) {
        const u16* kp = kb + (size_t)(nt * 16 + c) * DK + q * 8;
        bf16x8 b0 = *(const bf16x8*)(kp);
        bf16x8 b1 = *(const bf16x8*)(kp + 32);
        sc[nt] = __builtin_amdgcn_mfma_f32_16x16x32_bf16(a0, b0, sc[nt], 0, 0, 0);
        sc[nt] = __builtin_amdgcn_mfma_f32_16x16x32_bf16(a1, b1, sc[nt], 0, 0, 0);
    }

    // ---- softmax over 256 cols, entirely in registers ----
    float mx[4] = {-1e30f, -1e30f, -1e30f, -1e30f};
#pragma unroll
    for (int nt = 0; nt < 16; ++nt) {
        sc[nt] *= 0.125f;   // 1/sqrt(DK)
#pragma unroll
        for (int r = 0; r < 4; ++r) mx[r] = fmaxf(mx[r], sc[nt][r]);
    }
#pragma unroll
    for (int d = 1; d < 16; d <<= 1)
#pragma unroll
        for (int r = 0; r < 4; ++r) mx[r] = fmaxf(mx[r], __shfl_xor(mx[r], d, 64));

    float sm[4] = {0.f, 0.f, 0.f, 0.f};
#pragma unroll
    for (int nt = 0; nt < 16; ++nt)
#pragma unroll
        for (int r = 0; r < 4; ++r) {
            float e = __expf(sc[nt][r] - mx[r]);
            sc[nt][r] = e;
            sm[r] += e;
        }
#pragma unroll
    for (int d = 1; d < 16; d <<= 1)
#pragma unroll
        for (int r = 0; r < 4; ++r) sm[r] += __shfl_xor(sm[r], d, 64);
    float inv[4];
#pragma unroll
    for (int r = 0; r < 4; ++r) inv[r] = 1.0f / sm[r];

    // ---- P: C-layout regs -> LDS (row-major) for A-operand re-read ----
#pragma unroll
    for (int nt = 0; nt < 16; ++nt)
#pragma unroll
        for (int r = 0; r < 4; ++r)
            Pl[w * 16 + q * 4 + r][nt * 16 + c] = f2bf(sc[nt][r] * inv[r]);

    // ---- PV: out[16 x 64] per wave; A from LDS, B from VpT (L2) ----
    f32x4 ov[4];
#pragma unroll
    for (int nt = 0; nt < 4; ++nt) ov[nt] = (f32x4){0.f, 0.f, 0.f, 0.f};
    const u16* vb = VpT + (size_t)bh * DK * LK;
#pragma unroll
    for (int ks = 0; ks < 8; ++ks) {
        bf16x8 pa = *(const bf16x8*)&Pl[w * 16 + c][ks * 32 + q * 8];
#pragma unroll
        for (int nt = 0; nt < 4; ++nt) {
            bf16x8 vf = *(const bf16x8*)(vb + (size_t)(nt * 16 + c) * LK + ks * 32 + q * 8);
            ov[nt] = __builtin_amdgcn_mfma_f32_16x16x32_bf16(pa, vf, ov[nt], 0, 0, 0);
        }
    }

    // ---- stage out tile into reused Qs (as fp16!), then coalesced 16B stores ----
#pragma unroll
    for (int nt = 0; nt < 4; ++nt)
#pragma unroll
        for (int r = 0; r < 4; ++r)
            Qs[w * 16 + q * 4 + r][nt * 16 + c] = f2h(ov[nt][r]);

#pragma unroll
    for (int pass = 0; pass < 2; ++pass) {
        int lr  = w * 16 + pass * 8 + (lane >> 3);
        int col = (lane & 7) * 8;
        uint4 vv = *(uint4*)&Qs[lr][col];
        *(uint4*)(AO + ((size_t)b * SEQ + n0 + lr) * DMODEL + h * DK + col) = vv;
    }
}

// ---------------------------------------------------------------------------
// Kernel 3a (new): WoT[n][k] fp16 = Wo[k][n] f32. 6 MB traffic, ~3 us.
// ---------------------------------------------------------------------------
__global__ __launch_bounds__(256) void wo_convert(
    const float* __restrict__ Wo, u16* __restrict__ WoT)
{
    const int n0 = blockIdx.x * 64, k0 = blockIdx.y * 64;
    __shared__ float T[64][65];
    const int t = threadIdx.x;
    {
        int kr = (t >> 4) * 4;
        int nc = (t & 15) * 4;
#pragma unroll
        for (int i = 0; i < 4; ++i) {
            float4 v = *(const float4*)(Wo + (size_t)(k0 + kr + i) * DMODEL + n0 + nc);
            T[kr + i][nc + 0] = v.x; T[kr + i][nc + 1] = v.y;
            T[kr + i][nc + 2] = v.z; T[kr + i][nc + 3] = v.w;
        }
    }
    __syncthreads();
    int n = t >> 2, kc = (t & 3) * 16;
    u32 o[8];
#pragma unroll
    for (int j = 0; j < 8; ++j)
        o[j] = packh(T[kc + j * 2][n], T[kc + j * 2 + 1][n]);
    u16* dst = WoT + (size_t)(n0 + n) * DMODEL + k0 + kc;
    *(uint4*)(dst)     = make_uint4(o[0], o[1], o[2], o[3]);
    *(uint4*)(dst + 8) = make_uint4(o[4], o[5], o[6], o[7]);
}

// ---------------------------------------------------------------------------
// Kernel 3 (R6, MFMA): Out[16384][1024] = AO(f16) @ WoT^T(f16) + bo.
// m97 structure: 128x128 tile, BK=64, 4 waves 2x2 (each 64x64), f16 16x16x32.
// global_load_lds w16 staging; T2 XOR swizzle (col8 ^= row&7) applied as
// pre-swizzled global SOURCE (LDS dest linear, m173) + swizzled ds_read addr.
// Bank math: phys byte = row*128 + (col8^(row&7))*16 -> per quad, 16 lanes
// spread over all 8 16B-slots = 2 lanes/bank = free (m136).
// ---------------------------------------------------------------------------
#define OBM 128
#define OBN 128
#define OBK 64

__global__ __launch_bounds__(256) void out_gemm_mfma(
    const u16* __restrict__ AO, const u16* __restrict__ WoT,
    const float* __restrict__ bo, float* __restrict__ Out)
{
    const int c0 = blockIdx.x * OBN;
    const int r0 = blockIdx.y * OBM;
    const int t  = threadIdx.x;
    const int lane = t & 63;
    const int w  = t >> 6;
    const int wr = w >> 1, wc = w & 1;     // 2x2 wave grid, 64x64 each
    const int q  = lane >> 4, c = lane & 15;

    __shared__ u16 As[OBM * OBK];   // 16 KB, swizzled storage
    __shared__ u16 Bs[OBN * OBK];   // 16 KB

    f32x4 acc[4][4];
#pragma unroll
    for (int m = 0; m < 4; ++m)
#pragma unroll
        for (int n = 0; n < 4; ++n) acc[m][n] = (f32x4){0.f, 0.f, 0.f, 0.f};

    for (int k0 = 0; k0 < DMODEL; k0 += OBK) {
        // stage: 1024 x 16B per tile -> 4 issues/thread/tile.
        // LDS dest linear (li*16B); global source pre-swizzled (c8 ^ row&7).
#pragma unroll
        for (int i = 0; i < 4; ++i) {
            int li  = i * 256 + t;
            int row = li >> 3;
            int c8  = (li & 7) ^ (row & 7);
            gl2lds16(AO  + (size_t)(r0 + row) * DMODEL + k0 + c8 * 8, (u16*)As + (size_t)li * 8);
            gl2lds16(WoT + (size_t)(c0 + row) * DMODEL + k0 + c8 * 8, (u16*)Bs + (size_t)li * 8);
        }
        __syncthreads();   // drains vmcnt(0) then barrier (compiler-emitted)

#pragma unroll
        for (int s = 0; s < 2; ++s) {
            f16x8 af[4], bf[4];
#pragma unroll
            for (int m = 0; m < 4; ++m) {
                int row = wr * 64 + m * 16 + c;
                int c8  = (s * 4 + q) ^ (row & 7);
                af[m] = *(const f16x8*)&As[row * 64 + c8 * 8];
            }
#pragma unroll
            for (int n = 0; n < 4; ++n) {
                int row = wc * 64 + n * 16 + c;
                int c8  = (s * 4 + q) ^ (row & 7);
                bf[n] = *(const f16x8*)&Bs[row * 64 + c8 * 8];
            }
#pragma unroll
            for (int m = 0; m < 4; ++m)
#pragma unroll
                for (int n = 0; n < 4; ++n)
                    acc[m][n] = __builtin_amdgcn_mfma_f32_16x16x32_f16(af[m], bf[n], acc[m][n], 0, 0, 0);
        }
        __syncthreads();   // protect LDS before next tile's stage
    }

    // epilogue: C/D layout col=lane&15, row=q*4+r. 4x64B segments per store.
    float bv[4];
#pragma unroll
    for (int n = 0; n < 4; ++n) bv[n] = bo[c0 + wc * 64 + n * 16 + c];
#pragma unroll
    for (int m = 0; m < 4; ++m) {
        int rowb = r0 + wr * 64 + m * 16 + q * 4;
#pragma unroll
        for (int r = 0; r < 4; ++r) {
            float* dst = Out + (size_t)(rowb + r) * DMODEL + c0 + wc * 64 + c;
#pragma unroll
            for (int n = 0; n < 4; ++n) dst[n * 16] = acc[m][n][r] + bv[n];
        }
    }
}

// ---------------------------------------------------------------------------
extern "C" void kernel_launch(void* const* d_in, const int* in_sizes, int n_in,
                              void* d_out, int out_size, void* d_ws, size_t ws_size,
                              hipStream_t stream)
{
    const float* K   = (const float*)d_in[0];
    const float* Q   = (const float*)d_in[1];
    const float* V   = (const float*)d_in[2];
    const float* We  = (const float*)d_in[3];
    const float* be  = (const float*)d_in[4];
    const float* Wf  = (const float*)d_in[5];
    const float* bfp = (const float*)d_in[6];
    const float* Wo  = (const float*)d_in[7];
    const float* bo  = (const float*)d_in[8];
    float* Out = (float*)d_out;

    // workspace: KpT [bh][LK][DK] 2MB | VpT [bh][DK][LK] 2MB | AO 33.5MB | WoT 2MB
    u16* KpT = (u16*)d_ws;
    u16* VpT = KpT + (size_t)BH * LK * DK;
    u16* AO  = VpT + (size_t)BH * LK * DK;
    u16* WoT = AO  + (size_t)BB * SEQ * DMODEL;

    wo_convert<<<dim3(DMODEL / 64, DMODEL / 64), 256, 0, stream>>>(Wo, WoT);
    proj_kernel<<<dim3(4, 64, 2), 256, 0, stream>>>(K, V, We, be, Wf, bfp, KpT, VpT);
    attn_mfma<<<dim3(SEQ / 64, BH), 256, 0, stream>>>(Q, KpT, VpT, AO);
    out_gemm_mfma<<<dim3(DMODEL / OBN, (BB * SEQ) / OBM), 256, 0, stream>>>(AO, WoT, bo, Out);
}